// Round 11
// baseline (63.420 us; speedup 1.0000x reference)
//
#include <hip/hip_runtime.h>
#include <math.h>

#define T_SEQ 2048
#define C_DIM 512
#define B_SZ  2
#define NHEAD 8
#define HD    64
#define DP    128           // padded Q/K head dims (bf16) -> 256B rows
#define MTOT  1600
#define NTILE 32            // T_SEQ/64

typedef unsigned short u16t;
typedef unsigned int   u32t;
typedef float f32x4 __attribute__((ext_vector_type(4)));
typedef short s16x8 __attribute__((ext_vector_type(8)));

__device__ __forceinline__ u32t pack2(float a, float b) {
    u32t r;
    asm("v_cvt_pk_bf16_f32 %0, %1, %2" : "=v"(r) : "v"(a), "v"(b));
    return r;
}
__device__ __forceinline__ u16t f2bf(float f) {
    union { float f; u32t u; } v; v.f = f;
    u32t r = v.u + 0x7fffu + ((v.u >> 16) & 1u);
    return (u16t)(r >> 16);
}
__device__ __forceinline__ float bf2f(u16t h) {
    union { u32t u; float f; } v; v.u = (u32t)h << 16; return v.f;
}

#define GLD16(g, l) __builtin_amdgcn_global_load_lds( \
    (const __attribute__((address_space(1))) u32t*)(g), \
    (__attribute__((address_space(3))) u32t*)(l), 16, 0, 0)

// ---------------------------------------------------------------------------
// Merged prep: blocks [0,512): x transpose -> xT bf16 [b][t][c]
//              blocks [512, ...): weight/bias bf16 conversion   (R5/R8-proven)
// ---------------------------------------------------------------------------
__global__ __launch_bounds__(256)
void prep_kernel(const float* __restrict__ x, u16t* __restrict__ xT,
                 const float* __restrict__ Wq, const float* __restrict__ Wk,
                 const float* __restrict__ Wc, const float* __restrict__ Wqf,
                 const float* __restrict__ Wqd, const float* __restrict__ Wp,
                 const float* __restrict__ bq, const float* __restrict__ bk,
                 const float* __restrict__ bc, const float* __restrict__ bqf,
                 const float* __restrict__ bqd,
                 u16t* __restrict__ Wcat, u16t* __restrict__ Wpbf,
                 float* __restrict__ biascat)
{
    __shared__ float tile[64][65];
    int blk = blockIdx.x, tid = threadIdx.x;
    if (blk < 512) {
        int b = blk >> 8, rem = blk & 255;
        int c0 = (rem >> 5) << 6, t0 = (rem & 31) << 6;
        const float* xb = x + ((long long)b * C_DIM + c0) * T_SEQ + t0;
#pragma unroll
        for (int rr = 0; rr < 16; ++rr) {
            int row = rr * 4 + (tid >> 6);
            tile[row][tid & 63] = xb[(long long)row * T_SEQ + (tid & 63)];
        }
        __syncthreads();
        int tt = tid >> 2, cs = (tid & 3) * 16;
        u32t ov[8];
#pragma unroll
        for (int u = 0; u < 8; ++u)
            ov[u] = pack2(tile[cs + u * 2][tt], tile[cs + u * 2 + 1][tt]);
        u16t* dst = xT + ((long long)b * T_SEQ + t0 + tt) * C_DIM + c0 + cs;
        *(uint4*)(dst) = make_uint4(ov[0], ov[1], ov[2], ov[3]);
        *(uint4*)(dst + 8) = make_uint4(ov[4], ov[5], ov[6], ov[7]);
        return;
    }
    int r = blk - 512;
    if (r < MTOT) {
        const float* src;
        if (r < 512) src = Wq + (long long)r * C_DIM;
        else if (r < 1024) src = Wk + (long long)(r - 512) * C_DIM;
        else if (r < 1536) src = Wc + (long long)(r - 1024) * C_DIM;
        else if (r < 1568) src = Wqf + (long long)(r - 1536) * C_DIM;
        else src = Wqd + (long long)(r - 1568) * C_DIM;
        float2 v = *(const float2*)(src + tid * 2);
        *(u32t*)(Wcat + (long long)r * C_DIM + tid * 2) = pack2(v.x, v.y);
    } else if (r < MTOT + 512) {
        int rr = r - MTOT;
        float2 v = *(const float2*)(Wp + (long long)rr * C_DIM + tid * 2);
        *(u32t*)(Wpbf + (long long)rr * C_DIM + tid * 2) = pack2(v.x, v.y);
    } else {
        for (int i = tid; i < MTOT; i += 256) {
            float bv;
            if (i < 512) bv = bq[i];
            else if (i < 1024) bv = bk[i - 512];
            else if (i < 1536) bv = bc[i - 1024];
            else if (i < 1568) bv = bqf[i - 1536];
            else bv = bqd[i - 1568];
            biascat[i] = bv;
        }
    }
}

// ---------------------------------------------------------------------------
// bf16 MFMA GEMM, 64x64 tile, BK=64, double-buffered global_load_lds staging.
// (R3/R8-proven verbatim)
// ---------------------------------------------------------------------------
__global__ __launch_bounds__(256)
void gemm_kernel(const u16t* __restrict__ A, const u16t* __restrict__ Bm,
                 const float* __restrict__ biasv, const float* __restrict__ x,
                 u16t* __restrict__ Qbf, u16t* __restrict__ Kbf,
                 u16t* __restrict__ Vbf, float* __restrict__ fqd,
                 float* __restrict__ outp, int mode)
{
    __shared__ u16t At[2][64 * 64];
    __shared__ u16t Bt[2][64 * 64];
    int b = blockIdx.z, m0 = blockIdx.y * 64, n0 = blockIdx.x * 64;
    int tid = threadIdx.x, w = tid >> 6, lane = tid & 63;
    int l16 = lane & 15, l4 = lane >> 4;
    const u16t* Bb = Bm + (long long)b * T_SEQ * C_DIM;

    auto stage = [&](int kt, int bufi) {
        int k0 = kt * 64;
        const u16t* srcb = (w < 2) ? A + (long long)m0 * C_DIM + k0
                                   : Bb + (long long)n0 * C_DIM + k0;
        u16t* dstb = (w < 2) ? &At[bufi][0] : &Bt[bufi][0];
#pragma unroll
        for (int i = 0; i < 4; ++i) {
            int rb = (w & 1) * 32 + i * 8;
            int row = rb + (lane >> 3);
            int c = (lane & 7) ^ (row & 7);
            GLD16(srcb + (long long)row * C_DIM + c * 8, dstb + rb * 64);
        }
    };

    f32x4 acc[4] = {};
    stage(0, 0);
    for (int kt = 0; kt < 8; ++kt) {
        __syncthreads();
        if (kt < 7) stage(kt + 1, (kt + 1) & 1);
        const u16t* Bb2 = Bt[kt & 1];
        int nl = w * 16 + l16;
#pragma unroll
        for (int kb = 0; kb < 2; ++kb) {
            s16x8 bf = *(const s16x8*)(&Bb2[nl * 64 + (((kb * 4 + l4) ^ (l16 & 7)) * 8)]);
#pragma unroll
            for (int rt = 0; rt < 4; ++rt) {
                s16x8 af = *(const s16x8*)(&At[kt & 1][(rt * 16 + l16) * 64 + (((kb * 4 + l4) ^ (l16 & 7)) * 8)]);
                acc[rt] = __builtin_amdgcn_mfma_f32_16x16x32_bf16(af, bf, acc[rt], 0, 0, 0);
            }
        }
    }

    int n = n0 + w * 16 + l16;
    if (mode == 0) {
        if (m0 < 1024) {
            bool isQ = m0 < 512;
            int h = (isQ ? m0 : m0 - 512) >> 6;
            u16t* dst = (isQ ? Qbf : Kbf) + ((long long)(b * NHEAD + h) * T_SEQ + n) * DP;
            float sc = isQ ? 0.125f : 1.0f;
#pragma unroll
            for (int rt = 0; rt < 4; ++rt) {
                int d0 = (rt * 16 + l4 * 4) & 63;
                int m = m0 + rt * 16 + l4 * 4;
                float v0 = sc * (acc[rt][0] + biasv[m + 0]);
                float v1 = sc * (acc[rt][1] + biasv[m + 1]);
                float v2 = sc * (acc[rt][2] + biasv[m + 2]);
                float v3 = sc * (acc[rt][3] + biasv[m + 3]);
                *(uint2*)(dst + d0) = make_uint2(pack2(v0, v1), pack2(v2, v3));
            }
        } else if (m0 < 1536) {
#pragma unroll
            for (int rt = 0; rt < 4; ++rt)
#pragma unroll
                for (int j = 0; j < 4; ++j) {
                    int m = m0 + rt * 16 + l4 * 4 + j;
                    int c = m - 1024;
                    Vbf[((long long)b * C_DIM + c) * T_SEQ + n] = f2bf(acc[rt][j] + biasv[m]);
                }
        } else {
#pragma unroll
            for (int rt = 0; rt < 4; ++rt)
#pragma unroll
                for (int j = 0; j < 4; ++j) {
                    int m = m0 + rt * 16 + l4 * 4 + j;
                    fqd[((long long)b * 64 + (m - 1536)) * T_SEQ + n] = acc[rt][j] + biasv[m];
                }
        }
    } else {
#pragma unroll
        for (int rt = 0; rt < 4; ++rt)
#pragma unroll
            for (int j = 0; j < 4; ++j) {
                int m = m0 + rt * 16 + l4 * 4 + j;
                long long o = ((long long)b * C_DIM + m) * T_SEQ + n;
                outp[o] = acc[rt][j] + biasv[m] + x[o];
            }
    }
}

// ---------------------------------------------------------------------------
// Extension + knorm kernel (merged, R5/R8-proven)
// ---------------------------------------------------------------------------
__global__ __launch_bounds__(256)
void ext_kernel(const float* __restrict__ fqd, u16t* __restrict__ Qbf,
                u16t* __restrict__ Kbf, float* __restrict__ dcoef,
                float* __restrict__ knorm)
{
    int s = blockIdx.x * 256 + threadIdx.x;
    int bh = blockIdx.y, b = bh >> 3, h = bh & 7;
    const float* base = fqd + (long long)b * 64 * T_SEQ;
    float dsum = 0.f;
    u32t eq[4], ek[4];
#pragma unroll
    for (int f = 0; f < 4; ++f) {
        float fq = base[(long long)(h * 4 + f) * T_SEQ + s] * 0.5f;
        float zd = base[(long long)(32 + h * 4 + f) * T_SEQ + s];
        dsum += (float)(f + 1) / (1.f + __expf(-zd));
        float a = 2.0f * (float)s / (float)(f + 1);
        float cv = cospif(a), sv = sinpif(a);
        ek[f] = pack2(cv, sv);
        eq[f] = pack2(fq * cv, fq * sv);
    }
    uint4 z = make_uint4(0, 0, 0, 0);
    u16t* qrow = Qbf + ((long long)bh * T_SEQ + s) * DP;
    *(uint4*)(qrow + 64) = make_uint4(eq[0], eq[1], eq[2], eq[3]);
#pragma unroll
    for (int i = 0; i < 7; ++i) *(uint4*)(qrow + 72 + i * 8) = z;
    u16t* krow = Kbf + ((long long)bh * T_SEQ + s) * DP;
    *(uint4*)(krow + 64) = make_uint4(ek[0], ek[1], ek[2], ek[3]);
#pragma unroll
    for (int i = 0; i < 7; ++i) *(uint4*)(krow + 72 + i * 8) = z;
    dcoef[(long long)bh * T_SEQ + s] = 0.25f * dsum;

    float ss = 0.f;
#pragma unroll
    for (int i = 0; i < 8; ++i) {
        s16x8 v = *(const s16x8*)(krow + i * 8);
#pragma unroll
        for (int e = 0; e < 8; ++e) { float f = bf2f((u16t)v[e]); ss += f * f; }
    }
    float nrm = sqrtf(ss + 4.1f);
#pragma unroll
    for (int off = 1; off < 64; off <<= 1)
        nrm = fmaxf(nrm, __shfl_xor(nrm, off, 64));
    if ((threadIdx.x & 63) == 0)
        knorm[bh * NTILE + (s >> 6)] = nrm;
}

// ---------------------------------------------------------------------------
// MFMA flash attention: QBLK=32, 2 waves/block, grid 1024 -> 4 blocks/CU.
//  - Km stages K dims 0..63 (R10-proven); kb=2 freq dims direct from global
//  - LDS 36.9KB; same fragment/vote/epilogue algebra as R8/R10, w in {0,1}
// ---------------------------------------------------------------------------
__global__ __launch_bounds__(128)
void attn_kernel(const u16t* __restrict__ Qbf, const u16t* __restrict__ Kbf,
                 const u16t* __restrict__ Vbf, const float* __restrict__ dcoef,
                 const float* __restrict__ knorm, u16t* __restrict__ Rt)
{
    __shared__ u16t Km[2][64 * 64];       // 16KB: K dims 0..63 (64 t-rows)
    __shared__ u16t Vt[2][64 * 64];       // 16KB
    __shared__ u16t Pl[2][16 * 64];       // 4KB
    __shared__ u32t voteLds[2];

    int bh = blockIdx.y, b = bh >> 3, h = bh & 7;
    int s0 = blockIdx.x * 32;
    int j0 = s0 >> 6;                     // owning 64-wide t-tile
    int tid = threadIdx.x, w = tid >> 6, lane = tid & 63;
    int l16 = lane & 15, l4 = lane >> 4;
    const u16t* Qg = Qbf + (long long)bh * T_SEQ * DP;
    const u16t* Kg = Kbf + (long long)bh * T_SEQ * DP;
    const u16t* Vg = Vbf + ((long long)b * C_DIM + h * HD) * T_SEQ;
    int sl = w * 16 + l16;                // [0,32)
    int sg = s0 + sl;

    s16x8 qf[3];
#pragma unroll
    for (int kb = 0; kb < 3; ++kb)
        qf[kb] = *(const s16x8*)(Qg + (long long)sg * DP + kb * 32 + l4 * 8);
    float qn2 = 0.f;
#pragma unroll
    for (int kb = 0; kb < 3; ++kb)
#pragma unroll
        for (int e = 0; e < 8; ++e) { float f = bf2f((u16t)qf[kb][e]); qn2 += f * f; }
    qn2 += __shfl_xor(qn2, 16, 64);
    qn2 += __shfl_xor(qn2, 32, 64);
    float qn = sqrtf(qn2);
    float dc = dcoef[(long long)bh * T_SEQ + sg];
    float mrun = -1e30f, lrun = 0.f;
    f32x4 O4[4] = {};

    auto stageKV = [&](int tt0, int bufi) {
        // K: 32 t-rows per wave (8 rows x 8 chunks per iter)
#pragma unroll
        for (int i = 0; i < 4; ++i) {
            int rb = w * 32 + i * 8;
            int row = rb + (lane >> 3);
            int c = (lane & 7) ^ (row & 7);
            GLD16(Kg + (long long)(tt0 + row) * DP + c * 8, &Km[bufi][rb * 64]);
        }
        // V: 32 c-cols per wave
#pragma unroll
        for (int i = 0; i < 4; ++i) {
            int cb = w * 32 + i * 8;
            int cc = cb + (lane >> 3);
            int tc = (lane & 7) ^ (cc & 7);
            GLD16(Vg + (long long)cc * T_SEQ + tt0 + tc * 8, &Vt[bufi][cb * 64]);
        }
    };

    auto compute_tile = [&](int tj, int bufi, bool diag) {
        const u16t* Kb = Km[bufi];
        const u16t* Vb = Vt[bufi];
        int t0 = tj * 64;
        f32x4 sacc[4] = {};
#pragma unroll
        for (int kb = 0; kb < 2; ++kb)
#pragma unroll
            for (int rt = 0; rt < 4; ++rt) {
                s16x8 af = *(const s16x8*)(&Kb[(rt * 16 + l16) * 64 + (((kb * 4 + l4) ^ (l16 & 7)) * 8)]);
                sacc[rt] = __builtin_amdgcn_mfma_f32_16x16x32_bf16(af, qf[kb], sacc[rt], 0, 0, 0);
            }
        // kb=2: freq-ext dims 64..95 direct from global (R10-proven)
#pragma unroll
        for (int rt = 0; rt < 4; ++rt) {
            s16x8 af2 = *(const s16x8*)(Kg + (long long)(t0 + rt * 16 + l16) * DP + 64 + l4 * 8);
            sacc[rt] = __builtin_amdgcn_mfma_f32_16x16x32_bf16(af2, qf[2], sacc[rt], 0, 0, 0);
        }
        float cm = mrun;
        float pv[4][4];
#pragma unroll
        for (int rt = 0; rt < 4; ++rt) {
            int tb = t0 + rt * 16 + l4 * 4;
#pragma unroll
            for (int j = 0; j < 4; ++j) {
                int t = tb + j;
                float v = sacc[rt][j] - fabsf((float)(t - sg)) * dc;
                if (diag && t == sg) v = -100.f;
                pv[rt][j] = v;
                cm = fmaxf(cm, v);
            }
        }
        cm = fmaxf(cm, __shfl_xor(cm, 16, 64));
        cm = fmaxf(cm, __shfl_xor(cm, 32, 64));
        if (__any(cm > mrun)) {
            float scale = __expf(mrun - cm);
            mrun = cm;
            lrun *= scale;
#pragma unroll
            for (int rt = 0; rt < 4; ++rt) O4[rt] *= scale;
        }
        float psum = 0.f;
#pragma unroll
        for (int rt = 0; rt < 4; ++rt)
#pragma unroll
            for (int j = 0; j < 4; ++j) {
                float p = __expf(pv[rt][j] - mrun);
                pv[rt][j] = p;
                psum += p;
            }
        psum += __shfl_xor(psum, 16, 64);
        psum += __shfl_xor(psum, 32, 64);
        lrun += psum;
#pragma unroll
        for (int rt = 0; rt < 4; ++rt) {
            int tl = rt * 16 + l4 * 4;
            int cp = (tl >> 3) ^ (l16 & 7);
            *(uint2*)(&Pl[w][l16 * 64 + cp * 8 + (tl & 7)]) =
                make_uint2(pack2(pv[rt][0], pv[rt][1]), pack2(pv[rt][2], pv[rt][3]));
        }
#pragma unroll
        for (int kb = 0; kb < 2; ++kb) {
            s16x8 pf = *(const s16x8*)(&Pl[w][l16 * 64 + (((kb * 4 + l4) ^ (l16 & 7)) * 8)]);
#pragma unroll
            for (int rt = 0; rt < 4; ++rt) {
                s16x8 vf = *(const s16x8*)(&Vb[(rt * 16 + l16) * 64 + (((kb * 4 + l4) ^ (l16 & 7)) * 8)]);
                O4[rt] = __builtin_amdgcn_mfma_f32_16x16x32_bf16(vf, pf, O4[rt], 0, 0, 0);
            }
        }
    };

    // ---- phase 1: diagonal band ----
    int seq[3]; int ns = 0;
    seq[ns++] = j0;
    if (j0 + 1 < NTILE) seq[ns++] = j0 + 1;
    if (j0 > 0) seq[ns++] = j0 - 1;
    stageKV(seq[0] * 64, 0);
    for (int i = 0; i < ns; ++i) {
        __syncthreads();
        if (i + 1 < ns) stageKV(seq[i + 1] * 64, (i + 1) & 1);
        compute_tile(seq[i], i & 1, seq[i] == j0);
    }

    // ---- phase 2: Cauchy-Schwarz bounds (conservative minD, full-tile) ----
    u32t mask = 0;
    const float* knb = knorm + bh * NTILE;
    for (int j = 0; j < NTILE; ++j) {
        int d = j > j0 ? j - j0 : j0 - j;
        if (d <= 1) continue;
        float minD = (float)((d - 1) * 64 + 1);
        float bound = qn * knb[j] - dc * minD;
        if (__any(bound > mrun - 15.f)) mask |= 1u << j;
    }
    if (lane == 0) voteLds[w] = mask;
    __syncthreads();
    mask = voteLds[0] | voteLds[1];

    // ---- phase 3: surviving far tiles ----
    int parity = ns & 1;
    u32t rem = mask;
    if (rem) {
        int j = (int)__builtin_ctz(rem);
        stageKV(j * 64, parity);
        while (true) {
            rem &= rem - 1;
            __syncthreads();
            int nj = rem ? (int)__builtin_ctz(rem) : -1;
            if (nj >= 0) stageKV(nj * 64, parity ^ 1);
            compute_tile(j, parity, false);
            if (nj < 0) break;
            parity ^= 1;
            j = nj;
        }
    }

    // ---- epilogue (reuse Km[0] rows 0..31 as transpose bounce) ----
    __syncthreads();
    float inv = 1.f / lrun;
#pragma unroll
    for (int rt = 0; rt < 4; ++rt) {
        O4[rt] *= inv;
        int cb = rt * 16 + l4 * 4;
        int cp = (cb >> 3) ^ (sl & 7);
        *(uint2*)(&Km[0][sl * 64 + cp * 8 + (cb & 7)]) =
            make_uint2(pack2(O4[rt][0], O4[rt][1]), pack2(O4[rt][2], O4[rt][3]));
    }
    __syncthreads();
    {
        int row = tid >> 2;                 // 128 threads -> rows 0..31
        int rsw = row & 7;
        u16t* dst = Rt + ((long long)b * T_SEQ + s0 + row) * C_DIM + h * HD;
#pragma unroll
        for (int i = 0; i < 2; ++i) {
            int cc = (tid & 3) + i * 4;
            uint4 v = *(const uint4*)(&Km[0][row * 64 + ((cc ^ rsw) * 8)]);
            *(uint4*)(dst + cc * 8) = v;
        }
    }
}

// ---------------------------------------------------------------------------
extern "C" void kernel_launch(void* const* d_in, const int* in_sizes, int n_in,
                              void* d_out, int out_size, void* d_ws, size_t ws_size,
                              hipStream_t stream)
{
    const float* x   = (const float*)d_in[0];
    const float* Wq  = (const float*)d_in[1];
    const float* bq  = (const float*)d_in[2];
    const float* Wk  = (const float*)d_in[3];
    const float* bk  = (const float*)d_in[4];
    const float* Wc  = (const float*)d_in[5];
    const float* bc  = (const float*)d_in[6];
    const float* Wqf = (const float*)d_in[7];
    const float* bqf = (const float*)d_in[8];
    const float* Wqd = (const float*)d_in[9];
    const float* bqd = (const float*)d_in[10];
    const float* Wp  = (const float*)d_in[11];
    const float* bp  = (const float*)d_in[12];
    float* out = (float*)d_out;

    char* p = (char*)d_ws;
    u16t* Wcat = (u16t*)p;    p += (long long)MTOT * C_DIM * 2;
    u16t* Wpbf = (u16t*)p;    p += (long long)C_DIM * C_DIM * 2;
    float* biascat = (float*)p; p += MTOT * 4;
    u16t* xT = (u16t*)p;      p += (long long)B_SZ * T_SEQ * C_DIM * 2;
    u16t* Qbf = (u16t*)p;     p += (long long)16 * T_SEQ * DP * 2;
    u16t* Kbf = (u16t*)p;     p += (long long)16 * T_SEQ * DP * 2;
    u16t* Vbf = (u16t*)p;     p += (long long)B_SZ * C_DIM * T_SEQ * 2;
    float* fqd = (float*)p;   p += (long long)B_SZ * 64 * T_SEQ * 4;
    float* dcoef = (float*)p; p += (long long)16 * T_SEQ * 4;
    float* knorm = (float*)p; p += (long long)16 * NTILE * 4;
    u16t* Rt = (u16t*)p;      p += (long long)B_SZ * T_SEQ * C_DIM * 2;

    dim3 blk(256);
    hipLaunchKernelGGL(prep_kernel, dim3(512 + MTOT + 512 + 1), blk, 0, stream,
                       x, xT, Wq, Wk, Wc, Wqf, Wqd, Wp, bq, bk, bc, bqf, bqd,
                       Wcat, Wpbf, biascat);
    hipLaunchKernelGGL(gemm_kernel, dim3(T_SEQ / 64, MTOT / 64, B_SZ), blk, 0, stream,
                       Wcat, xT, biascat, nullptr, Qbf, Kbf, Vbf, fqd, nullptr, 0);
    hipLaunchKernelGGL(ext_kernel, dim3(T_SEQ / 256, 16), blk, 0, stream,
                       fqd, Qbf, Kbf, dcoef, knorm);
    hipLaunchKernelGGL(attn_kernel, dim3(T_SEQ / 32, 16), dim3(128), 0, stream,
                       Qbf, Kbf, Vbf, dcoef, knorm, Rt);
    hipLaunchKernelGGL(gemm_kernel, dim3(T_SEQ / 64, C_DIM / 64, B_SZ), blk, 0, stream,
                       Wpbf, Rt, bp, x, nullptr, nullptr, nullptr, nullptr, out, 1);
}

// Round 12
// 57.448 us; speedup vs baseline: 1.1040x; 1.1040x over previous
//
#include <hip/hip_runtime.h>
#include <math.h>

#define T_SEQ 2048
#define C_DIM 512
#define B_SZ  2
#define NHEAD 8
#define HD    64
#define DP    128           // padded Q/K head dims (bf16) -> 256B rows
#define MTOT  1600
#define NTILE 32            // T_SEQ/64

typedef unsigned short u16t;
typedef unsigned int   u32t;
typedef float f32x4 __attribute__((ext_vector_type(4)));
typedef short s16x8 __attribute__((ext_vector_type(8)));

__device__ __forceinline__ u32t pack2(float a, float b) {
    u32t r;
    asm("v_cvt_pk_bf16_f32 %0, %1, %2" : "=v"(r) : "v"(a), "v"(b));
    return r;
}
__device__ __forceinline__ u16t f2bf(float f) {
    union { float f; u32t u; } v; v.f = f;
    u32t r = v.u + 0x7fffu + ((v.u >> 16) & 1u);
    return (u16t)(r >> 16);
}
__device__ __forceinline__ float bf2f(u16t h) {
    union { u32t u; float f; } v; v.u = (u32t)h << 16; return v.f;
}

#define GLD16(g, l) __builtin_amdgcn_global_load_lds( \
    (const __attribute__((address_space(1))) u32t*)(g), \
    (__attribute__((address_space(3))) u32t*)(l), 16, 0, 0)

// ---------------------------------------------------------------------------
// Merged prep: blocks [0,512): x transpose -> xT bf16 [b][t][c]
//              blocks [512, ...): weight/bias bf16 conversion   (R5/R8-proven)
// ---------------------------------------------------------------------------
__global__ __launch_bounds__(256)
void prep_kernel(const float* __restrict__ x, u16t* __restrict__ xT,
                 const float* __restrict__ Wq, const float* __restrict__ Wk,
                 const float* __restrict__ Wc, const float* __restrict__ Wqf,
                 const float* __restrict__ Wqd, const float* __restrict__ Wp,
                 const float* __restrict__ bq, const float* __restrict__ bk,
                 const float* __restrict__ bc, const float* __restrict__ bqf,
                 const float* __restrict__ bqd,
                 u16t* __restrict__ Wcat, u16t* __restrict__ Wpbf,
                 float* __restrict__ biascat)
{
    __shared__ float tile[64][65];
    int blk = blockIdx.x, tid = threadIdx.x;
    if (blk < 512) {
        int b = blk >> 8, rem = blk & 255;
        int c0 = (rem >> 5) << 6, t0 = (rem & 31) << 6;
        const float* xb = x + ((long long)b * C_DIM + c0) * T_SEQ + t0;
#pragma unroll
        for (int rr = 0; rr < 16; ++rr) {
            int row = rr * 4 + (tid >> 6);
            tile[row][tid & 63] = xb[(long long)row * T_SEQ + (tid & 63)];
        }
        __syncthreads();
        int tt = tid >> 2, cs = (tid & 3) * 16;
        u32t ov[8];
#pragma unroll
        for (int u = 0; u < 8; ++u)
            ov[u] = pack2(tile[cs + u * 2][tt], tile[cs + u * 2 + 1][tt]);
        u16t* dst = xT + ((long long)b * T_SEQ + t0 + tt) * C_DIM + c0 + cs;
        *(uint4*)(dst) = make_uint4(ov[0], ov[1], ov[2], ov[3]);
        *(uint4*)(dst + 8) = make_uint4(ov[4], ov[5], ov[6], ov[7]);
        return;
    }
    int r = blk - 512;
    if (r < MTOT) {
        const float* src;
        if (r < 512) src = Wq + (long long)r * C_DIM;
        else if (r < 1024) src = Wk + (long long)(r - 512) * C_DIM;
        else if (r < 1536) src = Wc + (long long)(r - 1024) * C_DIM;
        else if (r < 1568) src = Wqf + (long long)(r - 1536) * C_DIM;
        else src = Wqd + (long long)(r - 1568) * C_DIM;
        float2 v = *(const float2*)(src + tid * 2);
        *(u32t*)(Wcat + (long long)r * C_DIM + tid * 2) = pack2(v.x, v.y);
    } else if (r < MTOT + 512) {
        int rr = r - MTOT;
        float2 v = *(const float2*)(Wp + (long long)rr * C_DIM + tid * 2);
        *(u32t*)(Wpbf + (long long)rr * C_DIM + tid * 2) = pack2(v.x, v.y);
    } else {
        for (int i = tid; i < MTOT; i += 256) {
            float bv;
            if (i < 512) bv = bq[i];
            else if (i < 1024) bv = bk[i - 512];
            else if (i < 1536) bv = bc[i - 1024];
            else if (i < 1568) bv = bqf[i - 1536];
            else bv = bqd[i - 1568];
            biascat[i] = bv;
        }
    }
}

// ---------------------------------------------------------------------------
// bf16 MFMA GEMM, 64x64 tile, BK=64, double-buffered global_load_lds staging.
// (R3/R8-proven verbatim)
// ---------------------------------------------------------------------------
__global__ __launch_bounds__(256)
void gemm_kernel(const u16t* __restrict__ A, const u16t* __restrict__ Bm,
                 const float* __restrict__ biasv, const float* __restrict__ x,
                 u16t* __restrict__ Qbf, u16t* __restrict__ Kbf,
                 u16t* __restrict__ Vbf, float* __restrict__ fqd,
                 float* __restrict__ outp, int mode)
{
    __shared__ u16t At[2][64 * 64];
    __shared__ u16t Bt[2][64 * 64];
    int b = blockIdx.z, m0 = blockIdx.y * 64, n0 = blockIdx.x * 64;
    int tid = threadIdx.x, w = tid >> 6, lane = tid & 63;
    int l16 = lane & 15, l4 = lane >> 4;
    const u16t* Bb = Bm + (long long)b * T_SEQ * C_DIM;

    auto stage = [&](int kt, int bufi) {
        int k0 = kt * 64;
        const u16t* srcb = (w < 2) ? A + (long long)m0 * C_DIM + k0
                                   : Bb + (long long)n0 * C_DIM + k0;
        u16t* dstb = (w < 2) ? &At[bufi][0] : &Bt[bufi][0];
#pragma unroll
        for (int i = 0; i < 4; ++i) {
            int rb = (w & 1) * 32 + i * 8;
            int row = rb + (lane >> 3);
            int c = (lane & 7) ^ (row & 7);
            GLD16(srcb + (long long)row * C_DIM + c * 8, dstb + rb * 64);
        }
    };

    f32x4 acc[4] = {};
    stage(0, 0);
    for (int kt = 0; kt < 8; ++kt) {
        __syncthreads();
        if (kt < 7) stage(kt + 1, (kt + 1) & 1);
        const u16t* Bb2 = Bt[kt & 1];
        int nl = w * 16 + l16;
#pragma unroll
        for (int kb = 0; kb < 2; ++kb) {
            s16x8 bf = *(const s16x8*)(&Bb2[nl * 64 + (((kb * 4 + l4) ^ (l16 & 7)) * 8)]);
#pragma unroll
            for (int rt = 0; rt < 4; ++rt) {
                s16x8 af = *(const s16x8*)(&At[kt & 1][(rt * 16 + l16) * 64 + (((kb * 4 + l4) ^ (l16 & 7)) * 8)]);
                acc[rt] = __builtin_amdgcn_mfma_f32_16x16x32_bf16(af, bf, acc[rt], 0, 0, 0);
            }
        }
    }

    int n = n0 + w * 16 + l16;
    if (mode == 0) {
        if (m0 < 1024) {
            bool isQ = m0 < 512;
            int h = (isQ ? m0 : m0 - 512) >> 6;
            u16t* dst = (isQ ? Qbf : Kbf) + ((long long)(b * NHEAD + h) * T_SEQ + n) * DP;
            float sc = isQ ? 0.125f : 1.0f;
#pragma unroll
            for (int rt = 0; rt < 4; ++rt) {
                int d0 = (rt * 16 + l4 * 4) & 63;
                int m = m0 + rt * 16 + l4 * 4;
                float v0 = sc * (acc[rt][0] + biasv[m + 0]);
                float v1 = sc * (acc[rt][1] + biasv[m + 1]);
                float v2 = sc * (acc[rt][2] + biasv[m + 2]);
                float v3 = sc * (acc[rt][3] + biasv[m + 3]);
                *(uint2*)(dst + d0) = make_uint2(pack2(v0, v1), pack2(v2, v3));
            }
        } else if (m0 < 1536) {
#pragma unroll
            for (int rt = 0; rt < 4; ++rt)
#pragma unroll
                for (int j = 0; j < 4; ++j) {
                    int m = m0 + rt * 16 + l4 * 4 + j;
                    int c = m - 1024;
                    Vbf[((long long)b * C_DIM + c) * T_SEQ + n] = f2bf(acc[rt][j] + biasv[m]);
                }
        } else {
#pragma unroll
            for (int rt = 0; rt < 4; ++rt)
#pragma unroll
                for (int j = 0; j < 4; ++j) {
                    int m = m0 + rt * 16 + l4 * 4 + j;
                    fqd[((long long)b * 64 + (m - 1536)) * T_SEQ + n] = acc[rt][j] + biasv[m];
                }
        }
    } else {
#pragma unroll
        for (int rt = 0; rt < 4; ++rt)
#pragma unroll
            for (int j = 0; j < 4; ++j) {
                int m = m0 + rt * 16 + l4 * 4 + j;
                long long o = ((long long)b * C_DIM + m) * T_SEQ + n;
                outp[o] = acc[rt][j] + biasv[m] + x[o];
            }
    }
}

// ---------------------------------------------------------------------------
// Extension + knorm kernel (merged; knorm now MAIN-dims-only — the ext part
// is bounded exactly by 2*||q_ext|| since ||k_ext||^2 = 4 by construction)
// ---------------------------------------------------------------------------
__global__ __launch_bounds__(256)
void ext_kernel(const float* __restrict__ fqd, u16t* __restrict__ Qbf,
                u16t* __restrict__ Kbf, float* __restrict__ dcoef,
                float* __restrict__ knorm)
{
    int s = blockIdx.x * 256 + threadIdx.x;
    int bh = blockIdx.y, b = bh >> 3, h = bh & 7;
    const float* base = fqd + (long long)b * 64 * T_SEQ;
    float dsum = 0.f;
    u32t eq[4], ek[4];
#pragma unroll
    for (int f = 0; f < 4; ++f) {
        float fq = base[(long long)(h * 4 + f) * T_SEQ + s] * 0.5f;
        float zd = base[(long long)(32 + h * 4 + f) * T_SEQ + s];
        dsum += (float)(f + 1) / (1.f + __expf(-zd));
        float a = 2.0f * (float)s / (float)(f + 1);
        float cv = cospif(a), sv = sinpif(a);
        ek[f] = pack2(cv, sv);
        eq[f] = pack2(fq * cv, fq * sv);
    }
    uint4 z = make_uint4(0, 0, 0, 0);
    u16t* qrow = Qbf + ((long long)bh * T_SEQ + s) * DP;
    *(uint4*)(qrow + 64) = make_uint4(eq[0], eq[1], eq[2], eq[3]);
#pragma unroll
    for (int i = 0; i < 7; ++i) *(uint4*)(qrow + 72 + i * 8) = z;
    u16t* krow = Kbf + ((long long)bh * T_SEQ + s) * DP;
    *(uint4*)(krow + 64) = make_uint4(ek[0], ek[1], ek[2], ek[3]);
#pragma unroll
    for (int i = 0; i < 7; ++i) *(uint4*)(krow + 72 + i * 8) = z;
    dcoef[(long long)bh * T_SEQ + s] = 0.25f * dsum;

    float ss = 0.f;
#pragma unroll
    for (int i = 0; i < 8; ++i) {
        s16x8 v = *(const s16x8*)(krow + i * 8);
#pragma unroll
        for (int e = 0; e < 8; ++e) { float f = bf2f((u16t)v[e]); ss += f * f; }
    }
    float nrm = sqrtf(ss);                  // main 64 dims only
#pragma unroll
    for (int off = 1; off < 64; off <<= 1)
        nrm = fmaxf(nrm, __shfl_xor(nrm, off, 64));
    if ((threadIdx.x & 63) == 0)
        knorm[bh * NTILE + (s >> 6)] = nrm;
}

// ---------------------------------------------------------------------------
// MFMA flash attention (R8 structure) with TIGHTENED skip bound:
//   bound_lane = qnm*knm[j] + 2*qne - dc*minD_lane,  skip if all <= mrun-12
//   (two-part Cauchy-Schwarz + per-lane exact distance + margin 12;
//    skipped-tile contribution <= 64*e^-12 ~ 4e-4 per tile)
// ---------------------------------------------------------------------------
__global__ __launch_bounds__(256)
void attn_kernel(const u16t* __restrict__ Qbf, const u16t* __restrict__ Kbf,
                 const u16t* __restrict__ Vbf, const float* __restrict__ dcoef,
                 const float* __restrict__ knorm, u16t* __restrict__ Rt)
{
    __shared__ u16t Kt[2][64 * DP];       // 32KB
    __shared__ u16t Vt[2][64 * 64];       // 16KB
    __shared__ u16t Pl[4][16 * 64];       // 8KB
    __shared__ u32t voteLds[4];

    int bh = blockIdx.y, b = bh >> 3, h = bh & 7;
    int j0 = blockIdx.x;
    int s0 = j0 * 64;
    int tid = threadIdx.x, w = tid >> 6, lane = tid & 63;
    int l16 = lane & 15, l4 = lane >> 4;
    const u16t* Qg = Qbf + (long long)bh * T_SEQ * DP;
    const u16t* Kg = Kbf + (long long)bh * T_SEQ * DP;
    const u16t* Vg = Vbf + ((long long)b * C_DIM + h * HD) * T_SEQ;
    int sl = w * 16 + l16;
    int sg = s0 + sl;

    s16x8 qf[3];
#pragma unroll
    for (int kb = 0; kb < 3; ++kb)
        qf[kb] = *(const s16x8*)(Qg + (long long)sg * DP + kb * 32 + l4 * 8);
    // two-part norms: main (kb 0,1 = dims 0..63), ext (kb 2 = dims 64..95)
    float qm2 = 0.f, qe2 = 0.f;
#pragma unroll
    for (int kb = 0; kb < 2; ++kb)
#pragma unroll
        for (int e = 0; e < 8; ++e) { float f = bf2f((u16t)qf[kb][e]); qm2 += f * f; }
#pragma unroll
    for (int e = 0; e < 8; ++e) { float f = bf2f((u16t)qf[2][e]); qe2 += f * f; }
    qm2 += __shfl_xor(qm2, 16, 64);
    qm2 += __shfl_xor(qm2, 32, 64);
    qe2 += __shfl_xor(qe2, 16, 64);
    qe2 += __shfl_xor(qe2, 32, 64);
    float qnm = sqrtf(qm2), qne = sqrtf(qe2);
    float dc = dcoef[(long long)bh * T_SEQ + sg];
    float mrun = -1e30f, lrun = 0.f;
    f32x4 O4[4] = {};

    auto stageKV = [&](int tt0, int bufi) {
#pragma unroll
        for (int i = 0; i < 4; ++i) {
            int rb = w * 16 + i * 4;
            int row = rb + (lane >> 4);
            int c = (lane & 15) ^ (row & 7);
            GLD16(Kg + (long long)(tt0 + row) * DP + c * 8, &Kt[bufi][rb * DP]);
        }
#pragma unroll
        for (int i = 0; i < 2; ++i) {
            int cb = w * 16 + i * 8;
            int cc = cb + (lane >> 3);
            int tc = (lane & 7) ^ (cc & 7);
            GLD16(Vg + (long long)cc * T_SEQ + tt0 + tc * 8, &Vt[bufi][cb * 64]);
        }
    };

    auto compute_tile = [&](int tj, int bufi, bool diag) {
        const u16t* Kb = Kt[bufi];
        const u16t* Vb = Vt[bufi];
        int t0 = tj * 64;
        f32x4 sacc[4] = {};
#pragma unroll
        for (int kb = 0; kb < 3; ++kb)
#pragma unroll
            for (int rt = 0; rt < 4; ++rt) {
                s16x8 af = *(const s16x8*)(&Kb[(rt * 16 + l16) * DP + (((kb * 4 + l4) ^ (l16 & 7)) * 8)]);
                sacc[rt] = __builtin_amdgcn_mfma_f32_16x16x32_bf16(af, qf[kb], sacc[rt], 0, 0, 0);
            }
        float cm = mrun;
        float pv[4][4];
#pragma unroll
        for (int rt = 0; rt < 4; ++rt) {
            int tb = t0 + rt * 16 + l4 * 4;
#pragma unroll
            for (int j = 0; j < 4; ++j) {
                int t = tb + j;
                float v = sacc[rt][j] - fabsf((float)(t - sg)) * dc;
                if (diag && t == sg) v = -100.f;
                pv[rt][j] = v;
                cm = fmaxf(cm, v);
            }
        }
        cm = fmaxf(cm, __shfl_xor(cm, 16, 64));
        cm = fmaxf(cm, __shfl_xor(cm, 32, 64));
        if (__any(cm > mrun)) {
            float scale = __expf(mrun - cm);
            mrun = cm;
            lrun *= scale;
#pragma unroll
            for (int rt = 0; rt < 4; ++rt) O4[rt] *= scale;
        }
        float psum = 0.f;
#pragma unroll
        for (int rt = 0; rt < 4; ++rt)
#pragma unroll
            for (int j = 0; j < 4; ++j) {
                float p = __expf(pv[rt][j] - mrun);
                pv[rt][j] = p;
                psum += p;
            }
        psum += __shfl_xor(psum, 16, 64);
        psum += __shfl_xor(psum, 32, 64);
        lrun += psum;
#pragma unroll
        for (int rt = 0; rt < 4; ++rt) {
            int tl = rt * 16 + l4 * 4;
            int cp = (tl >> 3) ^ (l16 & 7);
            *(uint2*)(&Pl[w][l16 * 64 + cp * 8 + (tl & 7)]) =
                make_uint2(pack2(pv[rt][0], pv[rt][1]), pack2(pv[rt][2], pv[rt][3]));
        }
#pragma unroll
        for (int kb = 0; kb < 2; ++kb) {
            s16x8 pf = *(const s16x8*)(&Pl[w][l16 * 64 + (((kb * 4 + l4) ^ (l16 & 7)) * 8)]);
#pragma unroll
            for (int rt = 0; rt < 4; ++rt) {
                s16x8 vf = *(const s16x8*)(&Vb[(rt * 16 + l16) * 64 + (((kb * 4 + l4) ^ (l16 & 7)) * 8)]);
                O4[rt] = __builtin_amdgcn_mfma_f32_16x16x32_bf16(vf, pf, O4[rt], 0, 0, 0);
            }
        }
    };

    // ---- phase 1: diagonal band ----
    int seq[3]; int ns = 0;
    seq[ns++] = j0;
    if (j0 + 1 < NTILE) seq[ns++] = j0 + 1;
    if (j0 > 0) seq[ns++] = j0 - 1;
    stageKV(seq[0] * 64, 0);
    for (int i = 0; i < ns; ++i) {
        __syncthreads();
        if (i + 1 < ns) stageKV(seq[i + 1] * 64, (i + 1) & 1);
        compute_tile(seq[i], i & 1, seq[i] == j0);
    }

    // ---- phase 2: tightened bounds (two-part CS, per-lane minD, margin 12)
    u32t mask = 0;
    const float* knb = knorm + bh * NTILE;
    for (int j = 0; j < NTILE; ++j) {
        int d = j > j0 ? j - j0 : j0 - j;
        if (d <= 1) continue;
        float minD = (j > j0) ? (float)(j * 64 - sg)
                              : (float)(sg - (j * 64 + 63));
        float bound = qnm * knb[j] + 2.f * qne - dc * minD;
        if (__any(bound > mrun - 12.f)) mask |= 1u << j;
    }
    voteLds[w] = mask;
    __syncthreads();
    mask = voteLds[0] | voteLds[1] | voteLds[2] | voteLds[3];

    // ---- phase 3: surviving far tiles ----
    int parity = ns & 1;
    u32t rem = mask;
    if (rem) {
        int j = (int)__builtin_ctz(rem);
        stageKV(j * 64, parity);
        while (true) {
            rem &= rem - 1;
            __syncthreads();
            int nj = rem ? (int)__builtin_ctz(rem) : -1;
            if (nj >= 0) stageKV(nj * 64, parity ^ 1);
            compute_tile(j, parity, false);
            if (nj < 0) break;
            parity ^= 1;
            j = nj;
        }
    }

    // ---- epilogue ----
    __syncthreads();
    float inv = 1.f / lrun;
#pragma unroll
    for (int rt = 0; rt < 4; ++rt) {
        O4[rt] *= inv;
        int cb = rt * 16 + l4 * 4;
        int cp = (cb >> 3) ^ (sl & 7);
        *(uint2*)(&Kt[0][sl * 64 + cp * 8 + (cb & 7)]) =
            make_uint2(pack2(O4[rt][0], O4[rt][1]), pack2(O4[rt][2], O4[rt][3]));
    }
    __syncthreads();
    {
        int row = tid >> 2;
        int rsw = row & 7;
        u16t* dst = Rt + ((long long)b * T_SEQ + s0 + row) * C_DIM + h * HD;
#pragma unroll
        for (int i = 0; i < 2; ++i) {
            int cc = (tid & 3) + i * 4;
            uint4 v = *(const uint4*)(&Kt[0][row * 64 + ((cc ^ rsw) * 8)]);
            *(uint4*)(dst + cc * 8) = v;
        }
    }
}

// ---------------------------------------------------------------------------
extern "C" void kernel_launch(void* const* d_in, const int* in_sizes, int n_in,
                              void* d_out, int out_size, void* d_ws, size_t ws_size,
                              hipStream_t stream)
{
    const float* x   = (const float*)d_in[0];
    const float* Wq  = (const float*)d_in[1];
    const float* bq  = (const float*)d_in[2];
    const float* Wk  = (const float*)d_in[3];
    const float* bk  = (const float*)d_in[4];
    const float* Wc  = (const float*)d_in[5];
    const float* bc  = (const float*)d_in[6];
    const float* Wqf = (const float*)d_in[7];
    const float* bqf = (const float*)d_in[8];
    const float* Wqd = (const float*)d_in[9];
    const float* bqd = (const float*)d_in[10];
    const float* Wp  = (const float*)d_in[11];
    const float* bp  = (const float*)d_in[12];
    float* out = (float*)d_out;

    char* p = (char*)d_ws;
    u16t* Wcat = (u16t*)p;    p += (long long)MTOT * C_DIM * 2;
    u16t* Wpbf = (u16t*)p;    p += (long long)C_DIM * C_DIM * 2;
    float* biascat = (float*)p; p += MTOT * 4;
    u16t* xT = (u16t*)p;      p += (long long)B_SZ * T_SEQ * C_DIM * 2;
    u16t* Qbf = (u16t*)p;     p += (long long)16 * T_SEQ * DP * 2;
    u16t* Kbf = (u16t*)p;     p += (long long)16 * T_SEQ * DP * 2;
    u16t* Vbf = (u16t*)p;     p += (long long)B_SZ * C_DIM * T_SEQ * 2;
    float* fqd = (float*)p;   p += (long long)B_SZ * 64 * T_SEQ * 4;
    float* dcoef = (float*)p; p += (long long)16 * T_SEQ * 4;
    float* knorm = (float*)p; p += (long long)16 * NTILE * 4;
    u16t* Rt = (u16t*)p;      p += (long long)B_SZ * T_SEQ * C_DIM * 2;

    dim3 blk(256);
    hipLaunchKernelGGL(prep_kernel, dim3(512 + MTOT + 512 + 1), blk, 0, stream,
                       x, xT, Wq, Wk, Wc, Wqf, Wqd, Wp, bq, bk, bc, bqf, bqd,
                       Wcat, Wpbf, biascat);
    hipLaunchKernelGGL(gemm_kernel, dim3(T_SEQ / 64, MTOT / 64, B_SZ), blk, 0, stream,
                       Wcat, xT, biascat, nullptr, Qbf, Kbf, Vbf, fqd, nullptr, 0);
    hipLaunchKernelGGL(ext_kernel, dim3(T_SEQ / 256, 16), blk, 0, stream,
                       fqd, Qbf, Kbf, dcoef, knorm);
    hipLaunchKernelGGL(attn_kernel, dim3(T_SEQ / 64, 16), blk, 0, stream,
                       Qbf, Kbf, Vbf, dcoef, knorm, Rt);
    hipLaunchKernelGGL(gemm_kernel, dim3(T_SEQ / 64, C_DIM / 64, B_SZ), blk, 0, stream,
                       Wpbf, Rt, bp, x, nullptr, nullptr, nullptr, nullptr, out, 1);
}